// Round 1
// baseline (333.256 us; speedup 1.0000x reference)
//
#include <hip/hip_runtime.h>

// DetectionLoss: B=16 images, A=65536 anchors, T=32 targets, C=21 classes.
// Pipeline: match -> force-match overrides -> focal+hist1(+pos/bbox sums)
//           -> radix-select L1 -> refine L2 -> select L2 -> refine L3 -> select L3
//           -> finalize. Exact top-k SUM via 3-level (12/12/8 bit) radix select
// on float bit patterns with per-bin count+sum.

#define AN 65536
#define BN 16
#define TN 32
#define CN 21
#define NBINS1 4096
#define NBINS2 4096
#define NBINS3 256
#define FIXSCALE 17179869184.0f /* 2^34 */

struct Accum { unsigned num_pos; unsigned n_neg; double pos_sum; double bbox_sum; double all_sum; };
struct Chain { unsigned done; unsigned beta1; unsigned beta2; unsigned rem; double sumAbove; double topk; };

// ---------- shared math (must be bit-identical across kernels: _rn intrinsics, no contraction) ----------
__device__ __forceinline__ void softmax_row(const float* __restrict__ row, float* __restrict__ p) {
    float c[CN];
#pragma unroll
    for (int j = 0; j < CN; ++j) c[j] = row[j];
    float m = c[0];
#pragma unroll
    for (int j = 1; j < CN; ++j) m = fmaxf(m, c[j]);
    float s = 0.f;
#pragma unroll
    for (int j = 0; j < CN; ++j) { c[j] = __expf(__fsub_rn(c[j], m)); s = __fadd_rn(s, c[j]); }
    float inv = 1.0f / s;  // deterministic lowering, identical in every kernel
#pragma unroll
    for (int j = 0; j < CN; ++j) p[j] = __fmul_rn(c[j], inv);
}

__device__ __forceinline__ float focal_cell(float p, bool cellpos) {
    float pt = cellpos ? p : __fsub_rn(1.0f, p);
    float af = cellpos ? 0.25f : 0.75f;
    float om = __fsub_rn(1.0f, pt);
    float lg = __logf(fmaxf(pt, 1e-6f));
    return __fmul_rn(__fmul_rn(__fmul_rn(-af, om), om), lg);
}

__device__ __forceinline__ unsigned focal_bits(float fo) {
    unsigned bits = __float_as_uint(fo);
    if (bits == 0x80000000u) bits = 0u;  // canonicalize -0.0 (sorts equal to +0.0 in the reference)
    return bits;
}

// ---------- kernel A: matching ----------
__global__ __launch_bounds__(256) void match_kernel(
    const float4* __restrict__ anchors, const float4* __restrict__ tboxes,
    float* __restrict__ max_iou, unsigned char* __restrict__ best_t,
    unsigned long long* __restrict__ gbest)
{
    __shared__ float4 tbS[TN];
    __shared__ float iouS[256 * (TN + 1)];
    __shared__ float pbV[TN][8];
    __shared__ int   pbA[TN][8];
    int b = blockIdx.y, tid = threadIdx.x;
    int a = blockIdx.x * 256 + tid;
    if (tid < TN) tbS[tid] = tboxes[b * TN + tid];
    __syncthreads();
    float4 ab = anchors[a];
    float a1 = (ab.z - ab.x) * (ab.w - ab.y);
    float best = -1.0f; int bt = 0;
#pragma unroll
    for (int t = 0; t < TN; ++t) {
        float4 t4 = tbS[t];
        float x1 = fmaxf(ab.x, t4.x), y1 = fmaxf(ab.y, t4.y);
        float x2 = fminf(ab.z, t4.z), y2 = fminf(ab.w, t4.w);
        float inter = fmaxf(x2 - x1, 0.f) * fmaxf(y2 - y1, 0.f);
        float a2 = (t4.z - t4.x) * (t4.w - t4.y);
        float iou = inter / (a1 + a2 - inter + 1e-6f);
        iouS[tid * (TN + 1) + t] = iou;
        if (iou > best) { best = iou; bt = t; }  // strict >: first-occurrence argmax
    }
    max_iou[(size_t)b * AN + a] = best;
    best_t[(size_t)b * AN + a] = (unsigned char)bt;
    __syncthreads();
    {   // per-target block argmax: thread -> (target t = tid>>3, part p = tid&7 over rows [32p,32p+32))
        int t = tid >> 3, pp = tid & 7;
        float bv = -1.f; int ba = 0;
        for (int r = pp * 32; r < pp * 32 + 32; ++r) {
            float v = iouS[r * (TN + 1) + t];
            if (v > bv) { bv = v; ba = r; }
        }
        pbV[t][pp] = bv; pbA[t][pp] = ba;
    }
    __syncthreads();
    if (tid < TN) {
        float bv = -1.f; int ba = 0;
#pragma unroll
        for (int pp = 0; pp < 8; ++pp) {
            float v = pbV[tid][pp];
            if (v > bv) { bv = v; ba = pbA[tid][pp]; }
        }
        unsigned ga = blockIdx.x * 256 + (unsigned)ba;
        unsigned long long key =
            (((unsigned long long)__float_as_uint(bv)) << 32) | (unsigned long long)(unsigned)(~ga);
        atomicMax(&gbest[b * TN + tid], key);  // tie on iou -> larger ~ga -> smaller anchor idx
    }
}

// ---------- kernel B: force-match overrides ----------
__global__ void force_kernel(const unsigned long long* __restrict__ gbest,
                             unsigned char* __restrict__ ovr)
{
    int i = blockIdx.x * blockDim.x + threadIdx.x;
    if (i < BN * TN) {
        unsigned long long key = gbest[i];
        unsigned ga = ~(unsigned)(key & 0xFFFFFFFFull);
        int b = i / TN;
        ovr[(size_t)b * AN + ga] = 1;
    }
}

// ---------- kernel C: focal, sums, level-1 histogram ----------
__global__ __launch_bounds__(256) void main_kernel(
    const float* __restrict__ conf, const float4* __restrict__ bboxp,
    const float4* __restrict__ tboxes, const int* __restrict__ tlabels,
    const float* __restrict__ max_iou, const unsigned char* __restrict__ best_t,
    const unsigned char* __restrict__ ovr,
    unsigned* __restrict__ cnt1, double* __restrict__ sum1,
    Accum* __restrict__ acc)
{
    __shared__ unsigned long long h[NBINS1];   // packed: count<<51 | fixed-point sum (2^-34)
    __shared__ float4 tbS[TN];
    __shared__ int tlS[TN];
    __shared__ float rF[3][4];
    __shared__ int rI[2][4];
    int b = blockIdx.y, tid = threadIdx.x;
    int a = blockIdx.x * 256 + tid;
    for (int i = tid; i < NBINS1; i += 256) h[i] = 0ULL;
    if (tid < TN) { tbS[tid] = tboxes[b * TN + tid]; tlS[tid] = tlabels[b * TN + tid]; }
    __syncthreads();

    size_t idx = (size_t)b * AN + a;
    float mi = max_iou[idx];
    bool ov = ovr[idx] != 0;
    bool posA = (mi >= 0.5f) || ov;
    bool negA = (mi < 0.4f) && !ov;
    int bt = best_t[idx];
    int label = posA ? tlS[bt] : -1;

    float p[CN];
    softmax_row(conf + idx * CN, p);
    float fall = 0.f;
#pragma unroll
    for (int j = 0; j < CN; ++j) {
        float fo = focal_cell(p[j], j == label);
        fall += fo;
        if (negA) {
            unsigned bits = focal_bits(fo);
            atomicAdd(&h[bits >> 20],
                      (1ULL << 51) | (unsigned long long)(fo * FIXSCALE));
        }
    }
    float bper = 0.f;
    if (posA) {
        float4 b1 = bboxp[idx];
        float4 b2 = tbS[bt];
        float x1 = fmaxf(b1.x, b2.x), y1 = fmaxf(b1.y, b2.y);
        float x2 = fminf(b1.z, b2.z), y2 = fminf(b1.w, b2.w);
        float inter = fmaxf(x2 - x1, 0.f) * fmaxf(y2 - y1, 0.f);
        float a1 = (b1.z - b1.x) * (b1.w - b1.y);
        float a2 = (b2.z - b2.x) * (b2.w - b2.y);
        float un = a1 + a2 - inter;
        float iou = inter / (un + 1e-6f);
        float ex1 = fminf(b1.x, b2.x), ey1 = fminf(b1.y, b2.y);
        float ex2 = fmaxf(b1.z, b2.z), ey2 = fmaxf(b1.w, b2.w);
        float enc = (ex2 - ex1) * (ey2 - ey1);
        float giou = iou - (enc - un) / (enc + 1e-6f);
        float gl = 1.0f - giou;
        float l1 = 0.f, d, ad;
        d = b1.x - b2.x; ad = fabsf(d); l1 += (ad < 1.0f) ? (0.5f * d * d) : (ad - 0.5f);
        d = b1.y - b2.y; ad = fabsf(d); l1 += (ad < 1.0f) ? (0.5f * d * d) : (ad - 0.5f);
        d = b1.z - b2.z; ad = fabsf(d); l1 += (ad < 1.0f) ? (0.5f * d * d) : (ad - 0.5f);
        d = b1.w - b2.w; ad = fabsf(d); l1 += (ad < 1.0f) ? (0.5f * d * d) : (ad - 0.5f);
        l1 *= 0.25f;
        bper = gl + 0.5f * l1;
    }
    // block reduce 5 quantities
    float vall = fall, vpos = posA ? fall : 0.f, vb = bper;
    int inp = posA ? 1 : 0, inn = negA ? 1 : 0;
#pragma unroll
    for (int off = 32; off; off >>= 1) {
        vall += __shfl_down(vall, off, 64);
        vpos += __shfl_down(vpos, off, 64);
        vb   += __shfl_down(vb,   off, 64);
        inp  += __shfl_down(inp,  off, 64);
        inn  += __shfl_down(inn,  off, 64);
    }
    int wv = tid >> 6, ln = tid & 63;
    if (ln == 0) { rF[0][wv] = vall; rF[1][wv] = vpos; rF[2][wv] = vb; rI[0][wv] = inp; rI[1][wv] = inn; }
    __syncthreads();
    if (tid == 0) {
        float s0 = 0, s1 = 0, s2 = 0; int c0 = 0, c1 = 0;
        for (int w = 0; w < 4; ++w) { s0 += rF[0][w]; s1 += rF[1][w]; s2 += rF[2][w]; c0 += rI[0][w]; c1 += rI[1][w]; }
        atomicAdd(&acc[b].all_sum, (double)s0);
        atomicAdd(&acc[b].pos_sum, (double)s1);
        atomicAdd(&acc[b].bbox_sum, (double)s2);
        atomicAdd(&acc[b].num_pos, (unsigned)c0);
        atomicAdd(&acc[b].n_neg, (unsigned)c1);
    }
    // flush LDS histogram (h writes are all before the reduce __syncthreads)
    for (int i = tid; i < NBINS1; i += 256) {
        unsigned long long v = h[i];
        if (v) {
            atomicAdd(&cnt1[b * NBINS1 + i], (unsigned)(v >> 51));
            atomicAdd(&sum1[b * NBINS1 + i],
                      (double)(v & ((1ULL << 51) - 1ULL)) * (1.0 / (double)FIXSCALE));
        }
    }
}

// ---------- refine passes ----------
__global__ __launch_bounds__(256) void refine2_kernel(
    const float* __restrict__ conf, const float* __restrict__ max_iou,
    const unsigned char* __restrict__ ovr, const Chain* __restrict__ chains,
    unsigned* __restrict__ cnt2k, double* __restrict__ sum2k,
    unsigned* __restrict__ cnt2q, double* __restrict__ sum2q)
{
    int b = blockIdx.y;
    unsigned tk = chains[b * 2 + 0].done ? 0xFFFFFFFFu : chains[b * 2 + 0].beta1;
    unsigned tq = chains[b * 2 + 1].done ? 0xFFFFFFFFu : chains[b * 2 + 1].beta1;
    if (tk == 0xFFFFFFFFu && tq == 0xFFFFFFFFu) return;
    int a = blockIdx.x * 256 + threadIdx.x;
    size_t idx = (size_t)b * AN + a;
    float mi = max_iou[idx];
    if (!((mi < 0.4f) && (ovr[idx] == 0))) return;
    float p[CN];
    softmax_row(conf + idx * CN, p);
#pragma unroll
    for (int j = 0; j < CN; ++j) {
        float fo = focal_cell(p[j], false);
        unsigned bits = focal_bits(fo);
        unsigned hi = bits >> 20;
        if (hi == tk) {
            unsigned bin = (bits >> 8) & 0xFFFu;
            atomicAdd(&cnt2k[b * NBINS2 + bin], 1u);
            atomicAdd(&sum2k[b * NBINS2 + bin], (double)fo);
        }
        if (hi == tq) {
            unsigned bin = (bits >> 8) & 0xFFFu;
            atomicAdd(&cnt2q[b * NBINS2 + bin], 1u);
            atomicAdd(&sum2q[b * NBINS2 + bin], (double)fo);
        }
    }
}

__global__ __launch_bounds__(256) void refine3_kernel(
    const float* __restrict__ conf, const float* __restrict__ max_iou,
    const unsigned char* __restrict__ ovr, const Chain* __restrict__ chains,
    unsigned* __restrict__ cnt3k, double* __restrict__ sum3k,
    unsigned* __restrict__ cnt3q, double* __restrict__ sum3q)
{
    int b = blockIdx.y;
    const Chain c0 = chains[b * 2 + 0];
    const Chain c1 = chains[b * 2 + 1];
    unsigned tk = c0.done ? 0xFFFFFFFFu : ((c0.beta1 << 12) | c0.beta2);
    unsigned tq = c1.done ? 0xFFFFFFFFu : ((c1.beta1 << 12) | c1.beta2);
    if (tk == 0xFFFFFFFFu && tq == 0xFFFFFFFFu) return;
    int a = blockIdx.x * 256 + threadIdx.x;
    size_t idx = (size_t)b * AN + a;
    float mi = max_iou[idx];
    if (!((mi < 0.4f) && (ovr[idx] == 0))) return;
    float p[CN];
    softmax_row(conf + idx * CN, p);
#pragma unroll
    for (int j = 0; j < CN; ++j) {
        float fo = focal_cell(p[j], false);
        unsigned bits = focal_bits(fo);
        unsigned hi = bits >> 8;
        if (hi == tk) {
            unsigned bin = bits & 0xFFu;
            atomicAdd(&cnt3k[b * NBINS3 + bin], 1u);
            atomicAdd(&sum3k[b * NBINS3 + bin], (double)fo);
        }
        if (hi == tq) {
            unsigned bin = bits & 0xFFu;
            atomicAdd(&cnt3q[b * NBINS3 + bin], 1u);
            atomicAdd(&sum3q[b * NBINS3 + bin], (double)fo);
        }
    }
}

// ---------- radix-select level scan ----------
template <int NB>
__global__ __launch_bounds__(256) void select_kernel(
    int level,
    const unsigned* __restrict__ cntA, const double* __restrict__ sumA,
    const unsigned* __restrict__ cntB, const double* __restrict__ sumB,
    Chain* __restrict__ chains, const Accum* __restrict__ acc)
{
    int b = blockIdx.x, cid = blockIdx.y, tid = threadIdx.x;
    Chain* ch = &chains[b * 2 + cid];
    unsigned rem; double sumAbove;
    if (level == 0) {
        unsigned np = acc[b].num_pos, nn = acc[b].n_neg;
        bool active;
        if (cid == 0) { rem = min(3u * np, nn); active = (np > 0) && (nn > 0); }
        else          { rem = min(100u, nn);     active = (np == 0) && (nn > 0); }
        if (!active || rem == 0) { if (tid == 0) { ch->done = 1; ch->topk = 0.0; } return; }
        sumAbove = 0.0;
    } else {
        if (ch->done) return;
        rem = ch->rem;
        sumAbove = ch->sumAbove;
    }
    const unsigned* cnt = (cid == 0 ? cntA : cntB) + (size_t)b * NB;
    const double*  sum = (cid == 0 ? sumA : sumB) + (size_t)b * NB;
    constexpr int IPT = NB / 256;
    unsigned lc[IPT]; double ls[IPT];
    unsigned ccnt = 0; double csum = 0.0;
#pragma unroll
    for (int i = 0; i < IPT; ++i) {
        lc[i] = cnt[tid * IPT + i]; ls[i] = sum[tid * IPT + i];
        ccnt += lc[i]; csum += ls[i];
    }
    __shared__ unsigned scnt[256];
    __shared__ double ssum[256];
    scnt[tid] = ccnt; ssum[tid] = csum;
    __syncthreads();
    for (int off = 1; off < 256; off <<= 1) {   // in-place suffix (from-top) scan
        unsigned vc = 0; double vs = 0.0;
        if (tid + off < 256) { vc = scnt[tid + off]; vs = ssum[tid + off]; }
        __syncthreads();
        scnt[tid] += vc; ssum[tid] += vs;
        __syncthreads();
    }
    unsigned total = scnt[0];
    unsigned aboveCnt = (tid < 255) ? scnt[tid + 1] : 0u;
    double aboveSum = (tid < 255) ? ssum[tid + 1] : 0.0;
    unsigned r = min(rem, total);  // defensive clamp
    if (r == 0) { if (tid == 0) { ch->done = 1; ch->topk = sumAbove; } return; }
    if (aboveCnt < r && aboveCnt + ccnt >= r) {   // exactly one thread
        unsigned acc2 = aboveCnt; double asum = aboveSum;
        int betaLocal = -1; unsigned remOut = 0;
        for (int i = IPT - 1; i >= 0; --i) {
            unsigned bc = lc[i];
            if (acc2 + bc >= r) { betaLocal = tid * IPT + i; remOut = r - acc2; break; }
            acc2 += bc; asum += ls[i];
        }
        if (level == 0)      { ch->beta1 = (unsigned)betaLocal; ch->rem = remOut; ch->sumAbove = sumAbove + asum; }
        else if (level == 1) { ch->beta2 = (unsigned)betaLocal; ch->rem = remOut; ch->sumAbove = sumAbove + asum; }
        else {
            unsigned vbits = (ch->beta1 << 20) | (ch->beta2 << 8) | (unsigned)betaLocal;
            double v = (double)__uint_as_float(vbits);
            ch->topk = sumAbove + asum + (double)remOut * v;
            ch->done = 1;
        }
    }
}

// ---------- finalize ----------
__global__ void finalize_kernel(const Accum* __restrict__ acc,
                                const Chain* __restrict__ chains,
                                float* __restrict__ out)
{
    __shared__ double cl[BN], bl[BN];
    int t = threadIdx.x;
    if (t < BN) {
        unsigned np = acc[t].num_pos, nn = acc[t].n_neg;
        double pos_sum = acc[t].pos_sum, all_sum = acc[t].all_sum, bbox_sum = acc[t].bbox_sum;
        unsigned k = min(3u * np, nn);
        unsigned k2 = min(100u, nn);
        double conf;
        if (np > 0) {
            if (nn > 0) conf = (pos_sum + chains[t * 2 + 0].topk) / (double)(np + k);
            else        conf = pos_sum / (double)np;
        } else {
            if (nn > 0) conf = chains[t * 2 + 1].topk / (double)(k2 > 0 ? k2 : 1u);
            else        conf = all_sum / (double)((size_t)AN * CN);
        }
        cl[t] = conf;
        bl[t] = (np > 0) ? (bbox_sum / (double)np) : 0.0;
    }
    __syncthreads();
    if (t == 0) {
        double cs = 0, bs = 0;
        for (int i = 0; i < BN; ++i) { cs += cl[i]; bs += bl[i]; }
        cs /= BN; bs /= BN;
        out[0] = (float)(cs + bs);
        out[1] = (float)cs;
        out[2] = (float)bs;
    }
}

extern "C" void kernel_launch(void* const* d_in, const int* in_sizes, int n_in,
                              void* d_out, int out_size, void* d_ws, size_t ws_size,
                              hipStream_t stream)
{
    (void)in_sizes; (void)n_in; (void)out_size; (void)ws_size;
    const float*  conf    = (const float*)d_in[0];
    const float4* bboxp   = (const float4*)d_in[1];
    const float4* anchors = (const float4*)d_in[2];
    const float4* tboxes  = (const float4*)d_in[3];
    const int*    tlabels = (const int*)d_in[4];
    float* out = (float*)d_out;
    char* ws = (char*)d_ws;
    size_t off = 0;
    auto alloc = [&](size_t bytes) -> void* {
        void* p = (void*)(ws + off);
        off = (off + bytes + 255) & ~(size_t)255;
        return p;
    };
    float*              max_iou = (float*)alloc((size_t)BN * AN * 4);
    unsigned char*      bestt   = (unsigned char*)alloc((size_t)BN * AN);
    size_t zstart = off;
    unsigned char*      ovr    = (unsigned char*)alloc((size_t)BN * AN);
    unsigned long long* gbest  = (unsigned long long*)alloc((size_t)BN * TN * 8);
    Accum*              acc    = (Accum*)alloc(BN * sizeof(Accum));
    Chain*              chains = (Chain*)alloc(BN * 2 * sizeof(Chain));
    unsigned* cnt1  = (unsigned*)alloc((size_t)BN * NBINS1 * 4);
    double*   sum1  = (double*)alloc((size_t)BN * NBINS1 * 8);
    unsigned* cnt2k = (unsigned*)alloc((size_t)BN * NBINS2 * 4);
    double*   sum2k = (double*)alloc((size_t)BN * NBINS2 * 8);
    unsigned* cnt2q = (unsigned*)alloc((size_t)BN * NBINS2 * 4);
    double*   sum2q = (double*)alloc((size_t)BN * NBINS2 * 8);
    unsigned* cnt3k = (unsigned*)alloc((size_t)BN * NBINS3 * 4);
    double*   sum3k = (double*)alloc((size_t)BN * NBINS3 * 8);
    unsigned* cnt3q = (unsigned*)alloc((size_t)BN * NBINS3 * 4);
    double*   sum3q = (double*)alloc((size_t)BN * NBINS3 * 8);
    size_t zbytes = off - zstart;
    hipMemsetAsync(ws + zstart, 0, zbytes, stream);

    dim3 gridA(AN / 256, BN);
    dim3 gridS(BN, 2);
    match_kernel<<<gridA, 256, 0, stream>>>(anchors, tboxes, max_iou, bestt, gbest);
    force_kernel<<<1, 512, 0, stream>>>(gbest, ovr);
    main_kernel<<<gridA, 256, 0, stream>>>(conf, bboxp, tboxes, tlabels, max_iou, bestt, ovr,
                                           cnt1, sum1, acc);
    select_kernel<NBINS1><<<gridS, 256, 0, stream>>>(0, cnt1, sum1, cnt1, sum1, chains, acc);
    refine2_kernel<<<gridA, 256, 0, stream>>>(conf, max_iou, ovr, chains, cnt2k, sum2k, cnt2q, sum2q);
    select_kernel<NBINS2><<<gridS, 256, 0, stream>>>(1, cnt2k, sum2k, cnt2q, sum2q, chains, acc);
    refine3_kernel<<<gridA, 256, 0, stream>>>(conf, max_iou, ovr, chains, cnt3k, sum3k, cnt3q, sum3q);
    select_kernel<NBINS3><<<gridS, 256, 0, stream>>>(2, cnt3k, sum3k, cnt3q, sum3q, chains, acc);
    finalize_kernel<<<1, 64, 0, stream>>>(acc, chains, out);
}